// Round 1
// baseline (1545.298 us; speedup 1.0000x reference)
//
#include <hip/hip_runtime.h>
#include <cstdint>
#include <cstddef>

#define N_NODES 20000
#define F_IN    8710
#define HID     128
#define NCLS    70
#define NEDGE   640000
#define KTILES  137            // ceil(8710/64)
#define KPAD    (KTILES * 64)  // 8768
#define KSPLIT0 69             // tiles in split 0 (split 1 gets 68)

typedef __attribute__((ext_vector_type(4))) float f32x4;
typedef __attribute__((ext_vector_type(8))) short bf16x8;

// ---- fp32 -> bf16 (round-to-nearest-even), bit math (no API dependence) ----
__device__ inline unsigned short f2bf(float f) {
    unsigned int u = __float_as_uint(f);
    u += 0x7fffu + ((u >> 16) & 1u);
    return (unsigned short)(u >> 16);
}

// K0: W1 [F_IN][HID] fp32 -> W1T bf16 [HID][KPAD], zero-padded K tail.
__global__ void prep_w1t(const float* __restrict__ W1, unsigned short* __restrict__ w1t) {
    int k = blockIdx.x * 256 + threadIdx.x;
    int n = blockIdx.y;
    if (k < KPAD) {
        float v = (k < F_IN) ? W1[(size_t)k * HID + n] : 0.0f;
        w1t[(size_t)n * KPAD + k] = f2bf(v);
    }
}

// K1: zero edge-count histogram
__global__ void zero_cnt(int* __restrict__ cnt) {
    int i = blockIdx.x * 256 + threadIdx.x;
    if (i < N_NODES) cnt[i] = 0;
}

// K2: histogram of dst
__global__ void count_deg(const int* __restrict__ edges, int* __restrict__ cnt) {
    int e = blockIdx.x * 256 + threadIdx.x;
    if (e < NEDGE) atomicAdd(&cnt[edges[NEDGE + e]], 1);
}

// K3: single-block exclusive scan -> rowptr, cursor; dinv = rsqrt(1+cnt) (self-loop)
#define SCAN_CH 20
__global__ __launch_bounds__(1024) void scan_k(const int* __restrict__ cnt,
                                               int* __restrict__ rowptr,
                                               int* __restrict__ cursor,
                                               float* __restrict__ dinv) {
    __shared__ int sums[1024];
    int t = threadIdx.x;
    int base = t * SCAN_CH;
    int s = 0;
    for (int j = 0; j < SCAN_CH; j++) {
        int i = base + j;
        if (i < N_NODES) s += cnt[i];
    }
    sums[t] = s;
    __syncthreads();
    for (int off = 1; off < 1024; off <<= 1) {
        int v = (t >= off) ? sums[t - off] : 0;
        __syncthreads();
        sums[t] += v;
        __syncthreads();
    }
    int run = sums[t] - s;  // exclusive prefix
    for (int j = 0; j < SCAN_CH; j++) {
        int i = base + j;
        if (i < N_NODES) {
            rowptr[i] = run;
            cursor[i] = run;
            int c = cnt[i];
            dinv[i] = rsqrtf(1.0f + (float)c);
            run += c;
        }
    }
    if (t == 1023) rowptr[N_NODES] = sums[1023];
}

// K4: scatter edges into CSR column array
__global__ void scatter_edges(const int* __restrict__ edges,
                              int* __restrict__ cursor,
                              int* __restrict__ colidx) {
    int e = blockIdx.x * 256 + threadIdx.x;
    if (e < NEDGE) {
        int s = edges[e];
        int d = edges[NEDGE + e];
        int pos = atomicAdd(&cursor[d], 1);
        colidx[pos] = s;
    }
}

// K5: GEMM1  hlin_part[z] = x @ W1  (bf16 MFMA, fp32->bf16 on the fly, split-K=2)
// BM=64, BN=128, BK=64, 256 threads (4 waves), wave tile 32x64 of 16x16x32 MFMAs.
#define BM 64
#define BK 64
#define LDK 72  // padded LDS row stride (bf16 elems): 144 B -> 2-way bank aliasing (free)
__global__ __launch_bounds__(256) void gemm1(const float* __restrict__ X,
                                             const unsigned short* __restrict__ W1T,
                                             float* __restrict__ outp) {
    __shared__ short lA[BM * LDK];
    __shared__ short lB[HID * LDK];
    int tid = threadIdx.x;
    int wave = tid >> 6, lane = tid & 63;
    int m0 = blockIdx.x * BM;
    int z = blockIdx.y;
    int t0 = z ? KSPLIT0 : 0;
    int t1 = z ? KTILES : KSPLIT0;
    int wm = (wave & 1) * 32;
    int wn = (wave >> 1) * 64;

    f32x4 acc[2][4];
#pragma unroll
    for (int a = 0; a < 2; a++)
#pragma unroll
        for (int b = 0; b < 4; b++) acc[a][b] = (f32x4)0.0f;

    // A staging map: 4 threads/row, each covers 16 k (8x float2)
    int ra = tid >> 2;
    int ka = (tid & 3) * 16;
    const float* Arow = X + (size_t)(m0 + ra) * F_IN;
    bool a_ok = (m0 + ra) < N_NODES;
    // B staging map: 2 threads/row, each covers 32 bf16 (4x 16B)
    int nb = tid >> 1;
    int kb = (tid & 1) * 32;
    const unsigned short* Brow = W1T + (size_t)nb * KPAD;

    for (int kt = t0; kt < t1; kt++) {
        int k0 = kt * BK;
        // stage A (fp32 -> bf16)
#pragma unroll
        for (int j = 0; j < 8; j++) {
            int kk = k0 + ka + 2 * j;
            float2 v = make_float2(0.0f, 0.0f);
            if (a_ok && (kk + 2) <= F_IN) v = *(const float2*)(Arow + kk);
            unsigned int p = ((unsigned int)f2bf(v.y) << 16) | (unsigned int)f2bf(v.x);
            *(unsigned int*)&lA[ra * LDK + ka + 2 * j] = p;
        }
        // stage B (bf16 copy)
#pragma unroll
        for (int j = 0; j < 4; j++) {
            uint4 v = *(const uint4*)(Brow + k0 + kb + 8 * j);
            *(uint4*)&lB[nb * LDK + kb + 8 * j] = v;
        }
        __syncthreads();
        // compute
#pragma unroll
        for (int kk = 0; kk < BK; kk += 32) {
            bf16x8 afrag[2], bfrag[4];
#pragma unroll
            for (int mt = 0; mt < 2; mt++) {
                int row = wm + mt * 16 + (lane & 15);
                afrag[mt] = *(const bf16x8*)&lA[row * LDK + kk + (lane >> 4) * 8];
            }
#pragma unroll
            for (int nt = 0; nt < 4; nt++) {
                int row = wn + nt * 16 + (lane & 15);
                bfrag[nt] = *(const bf16x8*)&lB[row * LDK + kk + (lane >> 4) * 8];
            }
#pragma unroll
            for (int mt = 0; mt < 2; mt++)
#pragma unroll
                for (int nt = 0; nt < 4; nt++)
                    acc[mt][nt] = __builtin_amdgcn_mfma_f32_16x16x32_bf16(
                        afrag[mt], bfrag[nt], acc[mt][nt], 0, 0, 0);
        }
        __syncthreads();
    }
    // epilogue: C/D layout col = lane&15, row = (lane>>4)*4 + j  [m89-verified]
    float* out = outp + (size_t)z * N_NODES * HID;
    int ccol = lane & 15, crow4 = (lane >> 4) * 4;
#pragma unroll
    for (int mt = 0; mt < 2; mt++) {
#pragma unroll
        for (int j = 0; j < 4; j++) {
            int m = m0 + wm + mt * 16 + crow4 + j;
            if (m < N_NODES) {
#pragma unroll
                for (int nt = 0; nt < 4; nt++)
                    out[(size_t)m * HID + wn + nt * 16 + ccol] = acc[mt][nt][j];
            }
        }
    }
}

// K6: reduce split-K partials
__global__ void reduce_k(const float* __restrict__ p, float* __restrict__ o) {
    size_t idx = ((size_t)blockIdx.x * 256 + threadIdx.x) * 4;
    if (idx < (size_t)N_NODES * HID) {
        float4 a = *(const float4*)(p + idx);
        float4 b = *(const float4*)(p + (size_t)N_NODES * HID + idx);
        float4 r;
        r.x = a.x + b.x; r.y = a.y + b.y; r.z = a.z + b.z; r.w = a.w + b.w;
        *(float4*)(o + idx) = r;
    }
}

// K7: layer-1 aggregation + bias + relu. One wave per node, lane covers 2 features.
__global__ __launch_bounds__(256) void agg1(const float* __restrict__ hlin,
                                            const int* __restrict__ rowptr,
                                            const int* __restrict__ colidx,
                                            const float* __restrict__ dinv,
                                            const float* __restrict__ b1,
                                            float* __restrict__ hout) {
    int node = blockIdx.x * 4 + (threadIdx.x >> 6);
    int lane = threadIdx.x & 63;
    if (node >= N_NODES) return;
    float di = dinv[node];
    float2 acc = ((const float2*)(hlin + (size_t)node * HID))[lane];
    acc.x *= di; acc.y *= di;   // self-loop: dinv_i * h_i (outer dinv_i applied later)
    int e0 = rowptr[node], e1 = rowptr[node + 1];
    for (int e = e0; e < e1; e++) {
        int s = colidx[e];
        float w = dinv[s];
        float2 v = ((const float2*)(hlin + (size_t)s * HID))[lane];
        acc.x += w * v.x;
        acc.y += w * v.y;
    }
    float2 b = ((const float2*)b1)[lane];
    float ox = di * acc.x + b.x;
    float oy = di * acc.y + b.y;
    ox = ox > 0.0f ? ox : 0.0f;
    oy = oy > 0.0f ? oy : 0.0f;
    ((float2*)(hout + (size_t)node * HID))[lane] = make_float2(ox, oy);
}

// K8: GEMM2  h2 = h1 @ W2  (tiny: LDS-staged fp32 VALU)
#define NPB 8
__global__ __launch_bounds__(256) void gemm2(const float* __restrict__ h1,
                                             const float* __restrict__ W2,
                                             float* __restrict__ h2) {
    __shared__ float sW[HID * NCLS];
    __shared__ float sH[NPB * HID];
    int t = threadIdx.x;
    int n0 = blockIdx.x * NPB;
    for (int i = t; i < HID * NCLS; i += 256) sW[i] = W2[i];
    for (int i = t; i < NPB * HID; i += 256) sH[i] = h1[(size_t)n0 * HID + i];
    __syncthreads();
    for (int o = t; o < NPB * NCLS; o += 256) {
        int ln = o / NCLS, c = o % NCLS;
        const float* hr = &sH[ln * HID];
        float a = 0.0f;
#pragma unroll 8
        for (int k = 0; k < HID; k++) a += hr[k] * sW[k * NCLS + c];
        h2[(size_t)(n0 + ln) * NCLS + c] = a;
    }
}

// K9: layer-2 aggregation + bias + softmax. One wave per node; lanes 0..34 hold 2 classes.
__global__ __launch_bounds__(256) void agg2_softmax(const float* __restrict__ h2,
                                                    const int* __restrict__ rowptr,
                                                    const int* __restrict__ colidx,
                                                    const float* __restrict__ dinv,
                                                    const float* __restrict__ b2,
                                                    float* __restrict__ outp) {
    int node = blockIdx.x * 4 + (threadIdx.x >> 6);
    int lane = threadIdx.x & 63;
    if (node >= N_NODES) return;
    float di = dinv[node];
    bool act = lane < 35;
    float2 acc = make_float2(0.0f, 0.0f);
    if (act) {
        float2 v = *(const float2*)(h2 + (size_t)node * NCLS + 2 * lane);
        acc.x = di * v.x; acc.y = di * v.y;
    }
    int e0 = rowptr[node], e1 = rowptr[node + 1];
    for (int e = e0; e < e1; e++) {
        int s = colidx[e];
        float w = dinv[s];
        if (act) {
            float2 v = *(const float2*)(h2 + (size_t)s * NCLS + 2 * lane);
            acc.x += w * v.x;
            acc.y += w * v.y;
        }
    }
    float lx = -1e30f, ly = -1e30f;
    if (act) {
        float2 b = *(const float2*)(b2 + 2 * lane);
        lx = di * acc.x + b.x;
        ly = di * acc.y + b.y;
    }
    float mx = fmaxf(lx, ly);
#pragma unroll
    for (int off = 32; off > 0; off >>= 1) mx = fmaxf(mx, __shfl_xor(mx, off, 64));
    float ex = 0.0f, ey = 0.0f;
    if (act) {
        ex = __expf(lx - mx);
        ey = __expf(ly - mx);
    }
    float sm = ex + ey;
#pragma unroll
    for (int off = 32; off > 0; off >>= 1) sm += __shfl_xor(sm, off, 64);
    if (act) {
        float inv = 1.0f / sm;
        *(float2*)(outp + (size_t)node * NCLS + 2 * lane) = make_float2(ex * inv, ey * inv);
    }
}

extern "C" void kernel_launch(void* const* d_in, const int* in_sizes, int n_in,
                              void* d_out, int out_size, void* d_ws, size_t ws_size,
                              hipStream_t stream) {
    const float* x     = (const float*)d_in[0];
    const int*   edges = (const int*)d_in[1];
    const float* W1    = (const float*)d_in[2];
    const float* b1    = (const float*)d_in[3];
    const float* W2    = (const float*)d_in[4];
    const float* b2    = (const float*)d_in[5];
    float* outp = (float*)d_out;

    char* ws = (char*)d_ws;
    size_t off = 0;
    auto alloc = [&](size_t bytes) {
        void* p = ws + off;
        off += (bytes + 255) & ~(size_t)255;
        return p;
    };
    unsigned short* w1t = (unsigned short*)alloc((size_t)HID * KPAD * 2);
    int*   cnt    = (int*)alloc((size_t)N_NODES * 4);
    int*   rowptr = (int*)alloc((size_t)(N_NODES + 1) * 4);
    int*   cursor = (int*)alloc((size_t)N_NODES * 4);
    float* dinv   = (float*)alloc((size_t)N_NODES * 4);
    int*   colidx = (int*)alloc((size_t)NEDGE * 4);
    float* hpart  = (float*)alloc((size_t)2 * N_NODES * HID * 4);  // split-K partials
    float* hlin1  = (float*)alloc((size_t)N_NODES * HID * 4);
    float* h1     = (float*)alloc((size_t)N_NODES * HID * 4);
    float* h2     = (float*)alloc((size_t)N_NODES * NCLS * 4);

    hipLaunchKernelGGL(prep_w1t, dim3((KPAD + 255) / 256, HID), dim3(256), 0, stream, W1, w1t);
    hipLaunchKernelGGL(zero_cnt, dim3((N_NODES + 255) / 256), dim3(256), 0, stream, cnt);
    hipLaunchKernelGGL(count_deg, dim3((NEDGE + 255) / 256), dim3(256), 0, stream, edges, cnt);
    hipLaunchKernelGGL(scan_k, dim3(1), dim3(1024), 0, stream, cnt, rowptr, cursor, dinv);
    hipLaunchKernelGGL(scatter_edges, dim3((NEDGE + 255) / 256), dim3(256), 0, stream, edges, cursor, colidx);
    hipLaunchKernelGGL(gemm1, dim3((N_NODES + BM - 1) / BM, 2), dim3(256), 0, stream, x, w1t, hpart);
    hipLaunchKernelGGL(reduce_k, dim3((N_NODES * HID / 4 + 255) / 256), dim3(256), 0, stream, hpart, hlin1);
    hipLaunchKernelGGL(agg1, dim3((N_NODES + 3) / 4), dim3(256), 0, stream, hlin1, rowptr, colidx, dinv, b1, h1);
    hipLaunchKernelGGL(gemm2, dim3(N_NODES / NPB), dim3(256), 0, stream, h1, W2, h2);
    hipLaunchKernelGGL(agg2_softmax, dim3((N_NODES + 3) / 4), dim3(256), 0, stream, h2, rowptr, colidx, dinv, b2, outp);
}

// Round 2
// 1172.664 us; speedup vs baseline: 1.3178x; 1.3178x over previous
//
#include <hip/hip_runtime.h>
#include <cstdint>
#include <cstddef>

#define N_NODES 20000
#define F_IN    8710
#define HID     128
#define NCLS    70
#define NEDGE   640000
#define KTILES  137            // ceil(8710/64)
#define KPAD    (KTILES * 64)  // 8768
#define BK      64
#define SPLITK  8

typedef __attribute__((ext_vector_type(4))) float f32x4;
typedef __attribute__((ext_vector_type(8))) short bf16x8;

// ---- fp32 -> bf16 RNE, bit math (used in prep pass) ----
__device__ inline unsigned short f2bf(float f) {
    unsigned int u = __float_as_uint(f);
    u += 0x7fffu + ((u >> 16) & 1u);
    return (unsigned short)(u >> 16);
}

// pack 2 fp32 -> 2 bf16 (lo=a, hi=b)
#if __has_builtin(__builtin_amdgcn_cvt_pk_bf16_f32)
typedef __attribute__((ext_vector_type(2))) __bf16 bf16x2t;
__device__ inline unsigned int pk2(float a, float b) {
    union { bf16x2t v; unsigned int u; } c;
    c.v = __builtin_amdgcn_cvt_pk_bf16_f32(a, b);
    return c.u;
}
#else
__device__ inline unsigned int pk2(float a, float b) {
    unsigned int ua = __float_as_uint(a), ub = __float_as_uint(b);
    ua += 0x7fffu + ((ua >> 16) & 1u);
    ub += 0x7fffu + ((ub >> 16) & 1u);
    return (ua >> 16) | (ub & 0xffff0000u);
}
#endif

// K0: W1 [F_IN][HID] -> W1T bf16 [HID][KPAD], coalesced via LDS transpose.
__global__ __launch_bounds__(256) void prep_w1t(const float* __restrict__ W1,
                                                unsigned short* __restrict__ w1t) {
    __shared__ float tl[64][65];
    int t = threadIdx.x;
    int k0 = blockIdx.x * 64, n0 = blockIdx.y * 64;
#pragma unroll
    for (int j = 0; j < 16; j++) {
        int l = j * 256 + t;
        int k = l >> 6, n = l & 63;
        float v = 0.0f;
        if (k0 + k < F_IN) v = W1[(size_t)(k0 + k) * HID + n0 + n];
        tl[k][n] = v;
    }
    __syncthreads();
#pragma unroll
    for (int j = 0; j < 16; j++) {
        int l = j * 256 + t;
        int n = l >> 6, k = l & 63;
        w1t[(size_t)(n0 + n) * KPAD + k0 + k] = f2bf(tl[k][n]);
    }
}

// K1: zero edge-count histogram
__global__ void zero_cnt(int* __restrict__ cnt) {
    int i = blockIdx.x * 256 + threadIdx.x;
    if (i < N_NODES) cnt[i] = 0;
}

// K2: histogram of dst
__global__ void count_deg(const int* __restrict__ edges, int* __restrict__ cnt) {
    int e = blockIdx.x * 256 + threadIdx.x;
    if (e < NEDGE) atomicAdd(&cnt[edges[NEDGE + e]], 1);
}

// K3: single-block exclusive scan -> rowptr, cursor; dinv = rsqrt(1+cnt)
#define SCAN_CH 20
__global__ __launch_bounds__(1024) void scan_k(const int* __restrict__ cnt,
                                               int* __restrict__ rowptr,
                                               int* __restrict__ cursor,
                                               float* __restrict__ dinv) {
    __shared__ int sums[1024];
    int t = threadIdx.x;
    int base = t * SCAN_CH;
    int s = 0;
    for (int j = 0; j < SCAN_CH; j++) {
        int i = base + j;
        if (i < N_NODES) s += cnt[i];
    }
    sums[t] = s;
    __syncthreads();
    for (int off = 1; off < 1024; off <<= 1) {
        int v = (t >= off) ? sums[t - off] : 0;
        __syncthreads();
        sums[t] += v;
        __syncthreads();
    }
    int run = sums[t] - s;
    for (int j = 0; j < SCAN_CH; j++) {
        int i = base + j;
        if (i < N_NODES) {
            rowptr[i] = run;
            cursor[i] = run;
            int c = cnt[i];
            dinv[i] = rsqrtf(1.0f + (float)c);
            run += c;
        }
    }
    if (t == 1023) rowptr[N_NODES] = sums[1023];
}

// K4: scatter edges into CSR column array
__global__ void scatter_edges(const int* __restrict__ edges,
                              int* __restrict__ cursor,
                              int* __restrict__ colidx) {
    int e = blockIdx.x * 256 + threadIdx.x;
    if (e < NEDGE) {
        int s = edges[e];
        int d = edges[NEDGE + e];
        int pos = atomicAdd(&cursor[d], 1);
        colidx[pos] = s;
    }
}

// K5: GEMM1 hpart[z] = x @ W1, bf16 MFMA.
// BM=128 (4 waves x 32 rows), BN=128(=HID), BK=64, split-K=8.
// A: direct global->reg fragments (lanes {l,l+16,l+32,l+48} cover 128B/row, coalesced).
// B: double-buffered LDS via global_load_lds(16B), XOR-swizzled chunks (conflict-free).
__global__ __launch_bounds__(256, 3) void gemm1(const float* __restrict__ X,
                                                const unsigned short* __restrict__ W1T,
                                                float* __restrict__ outp) {
    __shared__ unsigned short sB[2 * 8192];  // 2 x (128 rows x 64 bf16) = 32 KB
    int tid = threadIdx.x;
    int lane = tid & 63;
    int wv = __builtin_amdgcn_readfirstlane(tid >> 6);
    int m0 = blockIdx.x * 128;
    int z = blockIdx.y;
    int t0 = (z * KTILES) / SPLITK, t1 = ((z + 1) * KTILES) / SPLITK;

    // B staging map: physical chunk p stores logical (r = p>>3, j = (p&7)^(r&7)).
    int goffs[4];  // global short-offset sans k0, for issues i=0..3
#pragma unroll
    for (int i = 0; i < 4; i++) {
        int p = i * 256 + wv * 64 + lane;
        int r = p >> 3;
        int jl = (p & 7) ^ (r & 7);
        goffs[i] = r * KPAD + jl * 8;
    }

    // A fragment pointers (row clamped; OOB rows discarded at epilogue)
    const float* aptr[2];
#pragma unroll
    for (int mt = 0; mt < 2; mt++) {
        int row = m0 + wv * 32 + mt * 16 + (lane & 15);
        row = row < N_NODES ? row : N_NODES - 1;
        aptr[mt] = X + (size_t)row * F_IN + ((lane >> 4) * 8);
    }

    f32x4 acc[2][8];
#pragma unroll
    for (int mt = 0; mt < 2; mt++)
#pragma unroll
        for (int nt = 0; nt < 8; nt++) acc[mt][nt] = (f32x4)0.0f;

    auto stageB = [&](int kt, int buf) {
        int k0s = kt * BK;
#pragma unroll
        for (int i = 0; i < 4; i++) {
            const unsigned short* g = W1T + k0s + goffs[i];
            unsigned short* l = &sB[buf * 8192 + (i * 256 + wv * 64) * 8];
            __builtin_amdgcn_global_load_lds(
                (const __attribute__((address_space(1))) unsigned int*)g,
                (__attribute__((address_space(3))) unsigned int*)l, 16, 0, 0);
        }
    };

    stageB(t0, 0);
    __syncthreads();
    int cur = 0;

    for (int kt = t0; kt < t1; kt++) {
        int k0 = kt * BK;
        // --- A loads first (so their vmcnt wait doesn't drain the B prefetch) ---
        float2 q[2][2][4];  // [mt][kh][quarter] : 8 floats per frag
#pragma unroll
        for (int mt = 0; mt < 2; mt++)
#pragma unroll
            for (int kh = 0; kh < 2; kh++)
#pragma unroll
                for (int h = 0; h < 4; h++)
                    q[mt][kh][h] = *(const float2*)(aptr[mt] + k0 + kh * 32 + h * 2);
        // --- B prefetch for next tile ---
        if (kt + 1 < t1) stageB(kt + 1, cur ^ 1);
        // --- convert A to bf16 frags ---
        bf16x8 af[2][2];
#pragma unroll
        for (int mt = 0; mt < 2; mt++)
#pragma unroll
            for (int kh = 0; kh < 2; kh++) {
                union { bf16x8 v; unsigned int u[4]; } c;
#pragma unroll
                for (int h = 0; h < 4; h++) c.u[h] = pk2(q[mt][kh][h].x, q[mt][kh][h].y);
                af[mt][kh] = c.v;
            }
        // --- MFMA over current B buffer ---
        const unsigned short* bb = &sB[cur * 8192];
#pragma unroll
        for (int kh = 0; kh < 2; kh++) {
            int jx = (kh * 4 + (lane >> 4)) ^ (lane & 7);
#pragma unroll
            for (int half = 0; half < 2; half++) {
                bf16x8 bf[4];
#pragma unroll
                for (int q4 = 0; q4 < 4; q4++) {
                    int r = (half * 4 + q4) * 16 + (lane & 15);
                    bf[q4] = *(const bf16x8*)&bb[(r * 8 + jx) * 8];
                }
#pragma unroll
                for (int mt = 0; mt < 2; mt++)
#pragma unroll
                    for (int q4 = 0; q4 < 4; q4++)
                        acc[mt][half * 4 + q4] = __builtin_amdgcn_mfma_f32_16x16x32_bf16(
                            af[mt][kh], bf[q4], acc[mt][half * 4 + q4], 0, 0, 0);
            }
        }
        __syncthreads();
        cur ^= 1;
    }

    // epilogue: C/D layout col = lane&15, row = (lane>>4)*4 + j
    float* out = outp + (size_t)z * N_NODES * HID;
    int ccol = lane & 15, crow4 = (lane >> 4) * 4;
#pragma unroll
    for (int mt = 0; mt < 2; mt++) {
#pragma unroll
        for (int j = 0; j < 4; j++) {
            int m = m0 + wv * 32 + mt * 16 + crow4 + j;
            if (m < N_NODES) {
#pragma unroll
                for (int nt = 0; nt < 8; nt++)
                    out[(size_t)m * HID + nt * 16 + ccol] = acc[mt][nt][j];
            }
        }
    }
}

// K6: reduce split-K partials (8-way)
__global__ void reduce_k(const float* __restrict__ p, float* __restrict__ o) {
    size_t idx = ((size_t)blockIdx.x * 256 + threadIdx.x) * 4;
    if (idx < (size_t)N_NODES * HID) {
        float4 a = *(const float4*)(p + idx);
#pragma unroll
        for (int z = 1; z < SPLITK; z++) {
            float4 b = *(const float4*)(p + (size_t)z * N_NODES * HID + idx);
            a.x += b.x; a.y += b.y; a.z += b.z; a.w += b.w;
        }
        *(float4*)(o + idx) = a;
    }
}

// K7: layer-1 aggregation + bias + relu. One wave/node, lane covers 2 features.
// Edge loop unrolled x4: 4 independent gathers in flight.
__global__ __launch_bounds__(256) void agg1(const float* __restrict__ hlin,
                                            const int* __restrict__ rowptr,
                                            const int* __restrict__ colidx,
                                            const float* __restrict__ dinv,
                                            const float* __restrict__ b1,
                                            float* __restrict__ hout) {
    int node = blockIdx.x * 4 + (threadIdx.x >> 6);
    int lane = threadIdx.x & 63;
    if (node >= N_NODES) return;
    float di = dinv[node];
    float2 acc = ((const float2*)(hlin + (size_t)node * HID))[lane];
    acc.x *= di; acc.y *= di;
    int e0 = rowptr[node], e1 = rowptr[node + 1];
    int e = e0;
    for (; e + 4 <= e1; e += 4) {
        int s0 = colidx[e + 0], s1 = colidx[e + 1], s2 = colidx[e + 2], s3 = colidx[e + 3];
        float w0 = dinv[s0], w1 = dinv[s1], w2 = dinv[s2], w3 = dinv[s3];
        float2 v0 = ((const float2*)(hlin + (size_t)s0 * HID))[lane];
        float2 v1 = ((const float2*)(hlin + (size_t)s1 * HID))[lane];
        float2 v2 = ((const float2*)(hlin + (size_t)s2 * HID))[lane];
        float2 v3 = ((const float2*)(hlin + (size_t)s3 * HID))[lane];
        acc.x += w0 * v0.x; acc.y += w0 * v0.y;
        acc.x += w1 * v1.x; acc.y += w1 * v1.y;
        acc.x += w2 * v2.x; acc.y += w2 * v2.y;
        acc.x += w3 * v3.x; acc.y += w3 * v3.y;
    }
    for (; e < e1; e++) {
        int s = colidx[e];
        float w = dinv[s];
        float2 v = ((const float2*)(hlin + (size_t)s * HID))[lane];
        acc.x += w * v.x; acc.y += w * v.y;
    }
    float2 b = ((const float2*)b1)[lane];
    float ox = di * acc.x + b.x;
    float oy = di * acc.y + b.y;
    ox = ox > 0.0f ? ox : 0.0f;
    oy = oy > 0.0f ? oy : 0.0f;
    ((float2*)(hout + (size_t)node * HID))[lane] = make_float2(ox, oy);
}

// K8: GEMM2 h2 = h1 @ W2 (tiny: LDS-staged fp32 VALU)
#define NPB 8
__global__ __launch_bounds__(256) void gemm2(const float* __restrict__ h1,
                                             const float* __restrict__ W2,
                                             float* __restrict__ h2) {
    __shared__ float sW[HID * NCLS];
    __shared__ float sH[NPB * HID];
    int t = threadIdx.x;
    int n0 = blockIdx.x * NPB;
    for (int i = t; i < HID * NCLS; i += 256) sW[i] = W2[i];
    for (int i = t; i < NPB * HID; i += 256) sH[i] = h1[(size_t)n0 * HID + i];
    __syncthreads();
    for (int o = t; o < NPB * NCLS; o += 256) {
        int ln = o / NCLS, c = o % NCLS;
        const float* hr = &sH[ln * HID];
        float a = 0.0f;
#pragma unroll 8
        for (int k = 0; k < HID; k++) a += hr[k] * sW[k * NCLS + c];
        h2[(size_t)(n0 + ln) * NCLS + c] = a;
    }
}

// K9: layer-2 aggregation + bias + softmax. One wave/node; lanes 0..34 hold 2 classes.
__global__ __launch_bounds__(256) void agg2_softmax(const float* __restrict__ h2,
                                                    const int* __restrict__ rowptr,
                                                    const int* __restrict__ colidx,
                                                    const float* __restrict__ dinv,
                                                    const float* __restrict__ b2,
                                                    float* __restrict__ outp) {
    int node = blockIdx.x * 4 + (threadIdx.x >> 6);
    int lane = threadIdx.x & 63;
    if (node >= N_NODES) return;
    float di = dinv[node];
    bool act = lane < 35;
    int lidx = act ? lane : 0;
    float2 acc = make_float2(0.0f, 0.0f);
    {
        float2 v = *(const float2*)(h2 + (size_t)node * NCLS + 2 * lidx);
        acc.x = di * v.x; acc.y = di * v.y;
    }
    int e0 = rowptr[node], e1 = rowptr[node + 1];
    int e = e0;
    for (; e + 4 <= e1; e += 4) {
        int s0 = colidx[e + 0], s1 = colidx[e + 1], s2 = colidx[e + 2], s3 = colidx[e + 3];
        float w0 = dinv[s0], w1 = dinv[s1], w2 = dinv[s2], w3 = dinv[s3];
        float2 v0 = *(const float2*)(h2 + (size_t)s0 * NCLS + 2 * lidx);
        float2 v1 = *(const float2*)(h2 + (size_t)s1 * NCLS + 2 * lidx);
        float2 v2 = *(const float2*)(h2 + (size_t)s2 * NCLS + 2 * lidx);
        float2 v3 = *(const float2*)(h2 + (size_t)s3 * NCLS + 2 * lidx);
        acc.x += w0 * v0.x; acc.y += w0 * v0.y;
        acc.x += w1 * v1.x; acc.y += w1 * v1.y;
        acc.x += w2 * v2.x; acc.y += w2 * v2.y;
        acc.x += w3 * v3.x; acc.y += w3 * v3.y;
    }
    for (; e < e1; e++) {
        int s = colidx[e];
        float w = dinv[s];
        float2 v = *(const float2*)(h2 + (size_t)s * NCLS + 2 * lidx);
        acc.x += w * v.x; acc.y += w * v.y;
    }
    float lx = -1e30f, ly = -1e30f;
    if (act) {
        float2 b = *(const float2*)(b2 + 2 * lane);
        lx = di * acc.x + b.x;
        ly = di * acc.y + b.y;
    }
    float mx = fmaxf(lx, ly);
#pragma unroll
    for (int off = 32; off > 0; off >>= 1) mx = fmaxf(mx, __shfl_xor(mx, off, 64));
    float ex = 0.0f, ey = 0.0f;
    if (act) {
        ex = __expf(lx - mx);
        ey = __expf(ly - mx);
    }
    float sm = ex + ey;
#pragma unroll
    for (int off = 32; off > 0; off >>= 1) sm += __shfl_xor(sm, off, 64);
    if (act) {
        float inv = 1.0f / sm;
        *(float2*)(outp + (size_t)node * NCLS + 2 * lane) = make_float2(ex * inv, ey * inv);
    }
}

extern "C" void kernel_launch(void* const* d_in, const int* in_sizes, int n_in,
                              void* d_out, int out_size, void* d_ws, size_t ws_size,
                              hipStream_t stream) {
    const float* x     = (const float*)d_in[0];
    const int*   edges = (const int*)d_in[1];
    const float* W1    = (const float*)d_in[2];
    const float* b1    = (const float*)d_in[3];
    const float* W2    = (const float*)d_in[4];
    const float* b2    = (const float*)d_in[5];
    float* outp = (float*)d_out;

    char* ws = (char*)d_ws;
    size_t off = 0;
    auto alloc = [&](size_t bytes) {
        void* p = ws + off;
        off += (bytes + 255) & ~(size_t)255;
        return p;
    };
    unsigned short* w1t = (unsigned short*)alloc((size_t)HID * KPAD * 2);
    int*   cnt    = (int*)alloc((size_t)N_NODES * 4);
    int*   rowptr = (int*)alloc((size_t)(N_NODES + 1) * 4);
    int*   cursor = (int*)alloc((size_t)N_NODES * 4);
    float* dinv   = (float*)alloc((size_t)N_NODES * 4);
    int*   colidx = (int*)alloc((size_t)NEDGE * 4);
    float* hpart  = (float*)alloc((size_t)SPLITK * N_NODES * HID * 4);
    float* hlin1  = (float*)alloc((size_t)N_NODES * HID * 4);
    float* h1     = (float*)alloc((size_t)N_NODES * HID * 4);
    float* h2     = (float*)alloc((size_t)N_NODES * NCLS * 4);

    hipLaunchKernelGGL(prep_w1t, dim3(KTILES, 2), dim3(256), 0, stream, W1, w1t);
    hipLaunchKernelGGL(zero_cnt, dim3((N_NODES + 255) / 256), dim3(256), 0, stream, cnt);
    hipLaunchKernelGGL(count_deg, dim3((NEDGE + 255) / 256), dim3(256), 0, stream, edges, cnt);
    hipLaunchKernelGGL(scan_k, dim3(1), dim3(1024), 0, stream, cnt, rowptr, cursor, dinv);
    hipLaunchKernelGGL(scatter_edges, dim3((NEDGE + 255) / 256), dim3(256), 0, stream, edges, cursor, colidx);
    hipLaunchKernelGGL(gemm1, dim3((N_NODES + 127) / 128, SPLITK), dim3(256), 0, stream, x, w1t, hpart);
    hipLaunchKernelGGL(reduce_k, dim3((N_NODES * HID / 4 + 255) / 256), dim3(256), 0, stream, hpart, hlin1);
    hipLaunchKernelGGL(agg1, dim3((N_NODES + 3) / 4), dim3(256), 0, stream, hlin1, rowptr, colidx, dinv, b1, h1);
    hipLaunchKernelGGL(gemm2, dim3(N_NODES / NPB), dim3(256), 0, stream, h1, W2, h2);
    hipLaunchKernelGGL(agg2_softmax, dim3((N_NODES + 3) / 4), dim3(256), 0, stream, h2, rowptr, colidx, dinv, b2, outp);
}